// Round 7
// baseline (467.652 us; speedup 1.0000x reference)
//
#include <hip/hip_runtime.h>
#include <hip/hip_bf16.h>

// Problem constants (fixed by setup_inputs)
#define T_STEPS 512
#define BATCH   256
#define NN      128                 // n
#define NEMB    1024                // N
#define M_ROWS  (T_STEPS * BATCH)   // 131072
#define NOISE_K 0.13416407864998738f  // sqrt(2/alpha * sigma^2)
#define CH      8                   // steps per staged chunk
#define NCHUNK  (T_STEPS / CH)      // 64 (last chunk runs 7 steps)

typedef short s16x8 __attribute__((ext_vector_type(8)));
typedef float f32x4 __attribute__((ext_vector_type(4)));

__device__ __forceinline__ unsigned short f2bf(float f) {
  union { float f; unsigned u; } v; v.f = f;
  unsigned r = v.u + 0x7fffu + ((v.u >> 16) & 1u);  // RNE
  return (unsigned short)(r >> 16);
}
__device__ __forceinline__ float bf2f(unsigned short s) {
  union { unsigned u; float f; } v; v.u = ((unsigned)s) << 16;
  return v.f;
}
__device__ __forceinline__ float rdlane(float v, int l) {
  return __uint_as_float(__builtin_amdgcn_readlane(__float_as_uint(v), l));
}

// Light workgroup barrier with compiler-level fencing on BOTH sides:
// s_barrier's intrinsic is IntrNoMem -> without the trailing clobber the
// compiler may hoist the next step's ds_read above the barrier. lgkmcnt(0)
// before (my LDS writes committed), "" clobber after (no load hoisting).
// vmcnt deliberately NOT drained (states stores / prefetches stay in flight).
__device__ __forceinline__ void light_barrier() {
  asm volatile("s_waitcnt lgkmcnt(0)" ::: "memory");
  __builtin_amdgcn_s_barrier();
  asm volatile("" ::: "memory");
}

// ---------------------------------------------------------------------------
// Kernel 1: leaky-RNN recurrence. One block (128 thr = 2 waves) per batch.
// Each lane owns ONE full row i = tid: 128 FMAs with x broadcast via
// readlane->SGPR (v_fma reads x from SGPR; ZERO LDS reads in the matvec).
// ROUND-6 BUG (deterministic, absmax 0.405): w4 was declared [8] (32 floats)
// while the unrolled matvec statically indexed w4[0..31] -- OOB/UB for 3/4
// of the row. Fixed: w4[32] (full 128-float row in 128 VGPRs).
// x double-buffered in LDS (one light barrier per step). Noise staged in
// 8-step double-buffered LDS chunks (prefetch distance >> HBM latency).
// states (bf16) written to ws in (T, B, n) layout; row m = t*B + b.
// ---------------------------------------------------------------------------
__global__ __launch_bounds__(128, 1) void rnn_step_kernel(
    const float* __restrict__ u,          // (6, T, B)
    const float* __restrict__ rec_noise,  // (B, T, n)
    const float* __restrict__ inp_noise,  // (B, T, 6)
    const float* __restrict__ W_inp,      // (n, 6)
    const float* __restrict__ W_rec,      // (n, n)
    unsigned short* __restrict__ states)  // (T, B, n) bf16
{
  const int b    = blockIdx.x;
  const int tid  = threadIdx.x;   // 0..127 == row index i
  const int lane = tid & 63;

  __shared__ float xbuf[2][NN];
  __shared__ float rns[2][CH * NN];   // staged rec_noise chunk
  __shared__ float us[2][CH][8];      // staged (u + K*inp_noise) chunk

  // Full W_rec row in registers: 128 floats = 32 x f32x4 (statically indexed)
  const f32x4* wr = (const f32x4*)(W_rec + tid * NN);
  f32x4 w4[32];
  #pragma unroll
  for (int c = 0; c < 32; ++c) w4[c] = wr[c];

  float winp[6];
  #pragma unroll
  for (int j = 0; j < 6; ++j) winp[j] = W_inp[tid * 6 + j];

  const int ts6 = tid / 6, j6 = tid - ts6 * 6;  // (step, input) map for tid<48

  xbuf[0][tid] = 0.f;
  states[b * NN + tid] = 0;  // t=0 state is zero

  // prologue: stage chunk 0 (t = 0..7): 1024 floats by 128 threads (8 each)
  {
    const f32x4* src = (const f32x4*)(rec_noise + (size_t)b * T_STEPS * NN);
    *(f32x4*)&rns[0][tid * 8]     = src[tid * 2];
    *(f32x4*)&rns[0][tid * 8 + 4] = src[tid * 2 + 1];
    if (tid < 48) {
      float uu = u[j6 * (T_STEPS * BATCH) + ts6 * BATCH + b];
      float in = inp_noise[((size_t)b * T_STEPS + ts6) * 6 + j6];
      us[0][ts6][j6] = uu + NOISE_K * in;
    }
  }
  __syncthreads();  // one full drain in the prologue is fine

  float xr = 0.f;  // private copy of x[tid]
  for (int c = 0; c < NCHUNK; ++c) {
    const int cb = c & 1;

    // issue prefetch for chunk c+1 (lands during the 8 steps below)
    f32x4 pf0 = {0.f, 0.f, 0.f, 0.f}, pf1 = {0.f, 0.f, 0.f, 0.f};
    float u_pf = 0.f, in_pf = 0.f;
    if (c < NCHUNK - 1) {
      const f32x4* src =
          (const f32x4*)(rec_noise + ((size_t)b * T_STEPS + (c + 1) * CH) * NN);
      pf0 = src[tid * 2];
      pf1 = src[tid * 2 + 1];
      if (tid < 48) {
        const int tt = (c + 1) * CH + ts6;
        u_pf  = u[j6 * (T_STEPS * BATCH) + tt * BATCH + b];
        in_pf = inp_noise[((size_t)b * T_STEPS + tt) * 6 + j6];
      }
    }

    #pragma unroll
    for (int ts = 0; ts < CH; ++ts) {
      const int t = c * CH + ts;
      if (t > T_STEPS - 2) break;          // uniform: only trims last chunk
      const int cur = ts & 1, nxt = cur ^ 1;  // c*CH even -> parity = ts&1

      // wave-local x copy: lane l holds x[2l], x[2l+1]
      float2 vx = *(const float2*)&xbuf[cur][lane * 2];

      // full-row matvec: x broadcast lane->SGPR, w from VGPR, no LDS reads
      float a0 = 0.f, a1 = 0.f, a2 = 0.f, a3 = 0.f;
      #pragma unroll
      for (int kp = 0; kp < 64; ++kp) {      // k = 2*kp, 2*kp+1
        const float x0 = rdlane(vx.x, kp);
        const float x1 = rdlane(vx.y, kp);
        const float we0 = w4[kp >> 1][(kp & 1) * 2];
        const float we1 = w4[kp >> 1][(kp & 1) * 2 + 1];
        if (kp & 1) { a2 = fmaf(we0, x0, a2); a3 = fmaf(we1, x1, a3); }
        else        { a0 = fmaf(we0, x0, a0); a1 = fmaf(we1, x1, a1); }
      }
      float acc = (a0 + a1) + (a2 + a3);

      float inp = 0.f;
      #pragma unroll
      for (int j = 0; j < 6; ++j) inp = fmaf(winp[j], us[cb][ts][j], inp);

      const float pre = acc + inp;
      const float r   = pre > 0.f ? pre : 0.f;
      const float xn  = 0.9f * xr + 0.1f * (r + NOISE_K * rns[cb][ts * NN + tid]);
      xr = xn;

      xbuf[nxt][tid] = xn;                                  // publish new x
      states[((t + 1) * BATCH + b) * NN + tid] = f2bf(xn);  // no drain below

      light_barrier();  // lgkm-only + fenced both sides (no vmcnt drain)
    }

    // commit prefetched chunk to the other LDS buffer (compiler inserts the
    // vmcnt wait before these ds_writes; loads have had ~8 steps to land)
    if (c < NCHUNK - 1) {
      *(f32x4*)&rns[cb ^ 1][tid * 8]     = pf0;
      *(f32x4*)&rns[cb ^ 1][tid * 8 + 4] = pf1;
      if (tid < 48) us[cb ^ 1][ts6][j6] = u_pf + NOISE_K * in_pf;
      light_barrier();
    }
  }
}

// ---------------------------------------------------------------------------
// Kernel 2: states_embedded = states @ q, written transposed: out[j*M + m],
// plus fused W_out rows (jt==0 blocks only).
// Tile: 128 m x 64 j per block, 4 waves, K = 128. q in LDS (bf16, swizzled).
// ---------------------------------------------------------------------------
__global__ __launch_bounds__(256) void emb_kernel(
    const unsigned short* __restrict__ states,  // (M, n) bf16
    const float* __restrict__ q,                // (n, NEMB)
    const float* __restrict__ W_out,            // (2, n)
    float* __restrict__ out)                    // out[j*M + m]
{
  const int jt  = blockIdx.x;   // 0..15 (fast dim -> j-tiles of one m-panel co-resident)
  const int mt  = blockIdx.y;   // 0..1023
  const int tid = threadIdx.x;
  const int w   = tid >> 6;
  const int l   = tid & 63;
  const int lg  = l >> 4;       // 0..3
  const int lr  = l & 15;

  __shared__ unsigned short qt[64 * 128];  // [j][k], swizzled, 16 KB
  __shared__ float wos[2 * NN];            // W_out rows (used by jt==0)

  // stage q tile -> bf16 LDS (coalesced global reads)
  {
    const int j  = tid & 63;
    const int k0 = tid >> 6;
    #pragma unroll
    for (int kk = k0; kk < 128; kk += 4) {
      float v = q[kk * NEMB + jt * 64 + j];
      int k8 = kk >> 3, e = kk & 7;
      qt[j * 128 + ((k8 ^ (j & 7)) << 3) + e] = f2bf(v);
    }
  }
  if (jt == 0) wos[tid] = W_out[tid];

  // A fragments from global: row = l&15, k-chunk = (l>>4)*8 within each K=32
  s16x8 afrag[2][4];
  #pragma unroll
  for (int mf = 0; mf < 2; ++mf) {
    const int m = mt * 128 + w * 32 + mf * 16 + lr;
    const unsigned short* arow = states + m * NN;
    #pragma unroll
    for (int kc = 0; kc < 4; ++kc)
      afrag[mf][kc] = *(const s16x8*)(arow + kc * 32 + lg * 8);
  }
  __syncthreads();

  f32x4 acc[2][4] = {};
  #pragma unroll
  for (int kc = 0; kc < 4; ++kc) {
    s16x8 bfrag[4];
    #pragma unroll
    for (int jf = 0; jf < 4; ++jf) {
      const int jl = jf * 16 + lr;
      bfrag[jf] = *(const s16x8*)(qt + jl * 128 + ((((kc << 2) + lg) ^ (jl & 7)) << 3));
    }
    #pragma unroll
    for (int mf = 0; mf < 2; ++mf)
      #pragma unroll
      for (int jf = 0; jf < 4; ++jf)
        acc[mf][jf] = __builtin_amdgcn_mfma_f32_16x16x32_bf16(
            afrag[mf][kc], bfrag[jf], acc[mf][jf], 0, 0, 0);
  }

  // fused W_out (jt==0 blocks): per-lane partial over its k-chunks, reduce lg
  if (jt == 0) {
    #pragma unroll
    for (int mf = 0; mf < 2; ++mf) {
      float s0 = 0.f, s1 = 0.f;
      #pragma unroll
      for (int kc = 0; kc < 4; ++kc) {
        const int kb = kc * 32 + lg * 8;
        const s16x8 af = afrag[mf][kc];
        #pragma unroll
        for (int e = 0; e < 8; ++e) {
          const float x = bf2f((unsigned short)af[e]);
          s0 = fmaf(x, wos[kb + e], s0);
          s1 = fmaf(x, wos[NN + kb + e], s1);
        }
      }
      s0 += __shfl_xor(s0, 16); s0 += __shfl_xor(s0, 32);
      s1 += __shfl_xor(s1, 16); s1 += __shfl_xor(s1, 32);
      if (lg == 0) {
        const long m = (long)mt * 128 + w * 32 + mf * 16 + lr;
        out[(long)1024 * M_ROWS + m] = s0;
        out[(long)1025 * M_ROWS + m] = s1;
      }
    }
  }

  // epilogue: per-lane float4 along m (D: col=lane&15 -> j, row=(lane>>4)*4+reg -> m)
  #pragma unroll
  for (int mf = 0; mf < 2; ++mf) {
    const int m = mt * 128 + w * 32 + mf * 16 + lg * 4;
    #pragma unroll
    for (int jf = 0; jf < 4; ++jf) {
      const long j = jt * 64 + jf * 16 + lr;
      *(f32x4*)&out[j * M_ROWS + m] = acc[mf][jf];
    }
  }
}

extern "C" void kernel_launch(void* const* d_in, const int* in_sizes, int n_in,
                              void* d_out, int out_size, void* d_ws, size_t ws_size,
                              hipStream_t stream) {
  const float* u         = (const float*)d_in[0];
  const float* rec_noise = (const float*)d_in[1];
  const float* inp_noise = (const float*)d_in[2];
  const float* W_inp     = (const float*)d_in[3];
  const float* W_rec     = (const float*)d_in[4];
  const float* W_out     = (const float*)d_in[5];
  const float* q         = (const float*)d_in[6];
  float* out = (float*)d_out;
  unsigned short* states = (unsigned short*)d_ws;  // (T, B, n) bf16 = 33.6 MB

  rnn_step_kernel<<<dim3(BATCH), dim3(128), 0, stream>>>(
      u, rec_noise, inp_noise, W_inp, W_rec, states);

  dim3 g2(NEMB / 64, M_ROWS / 128);  // (16, 1024), jt fastest for A-panel L2 reuse
  emb_kernel<<<g2, dim3(256), 0, stream>>>(states, q, W_out, out);
}